// Round 4
// baseline (1983.688 us; speedup 1.0000x reference)
//
#include <hip/hip_runtime.h>

#define OUTSZ 524288  // elems per output level (64*32*16*16)

typedef float f4 __attribute__((ext_vector_type(4)));

// ---------------- grid-wide barrier (per-event counter, agent scope) --------
__device__ __forceinline__ void gsync(unsigned* bar, int ev, unsigned nb) {
    __syncthreads();
    if (threadIdx.x == 0) {
        __threadfence();  // release: writeback this XCD's L2
        __hip_atomic_fetch_add(bar + ev, 1u, __ATOMIC_ACQ_REL, __HIP_MEMORY_SCOPE_AGENT);
        while (__hip_atomic_load(bar + ev, __ATOMIC_ACQUIRE, __HIP_MEMORY_SCOPE_AGENT) < nb)
            __builtin_amdgcn_s_sleep(8);
        __threadfence();  // acquire: invalidate stale L1/L2 lines
    }
    __syncthreads();
}

// ---------------- cubic (Keys a=-0.5), matches jax.image.resize 'cubic' ----
__device__ __forceinline__ float cubic_w(float x) {
    x = fabsf(x);
    if (x >= 2.f) return 0.f;
    if (x >= 1.f) return ((-0.5f * x + 2.5f) * x - 4.f) * x + 2.f;
    return ((1.5f * x - 2.5f) * x) * x + 1.f;
}

template <int PN>
__device__ __forceinline__ void taps(int o, float* w, int& i0, int& n) {
    float sf = (o + 0.5f) * ((float)PN / 16.f) - 0.5f;
    int lo = (int)floorf(sf) - 1;
    int hi = lo + 3;
    if (lo < 0) lo = 0;
    if (hi > PN - 1) hi = PN - 1;
    n = hi - lo + 1;
    i0 = lo;
    float tot = 0.f;
    for (int i = 0; i < n; i++) {
        float ww = cubic_w(sf - (float)(lo + i));
        w[i] = ww;
        tot += ww;
    }
    float inv = 1.f / tot;
    for (int i = 0; i < n; i++) w[i] *= inv;
}

// ---- exact-order helpers (match numpy reference rounding; do not touch) ----
#define FMA4(D, A, B)                                                          \
    D = __builtin_fmaf((A).x, (B).x, D); D = __builtin_fmaf((A).y, (B).y, D);  \
    D = __builtin_fmaf((A).z, (B).z, D); D = __builtin_fmaf((A).w, (B).w, D)
#define DOT32(D)                                                               \
    FMA4(D, z0, w0); FMA4(D, z1, w1); FMA4(D, z2, w2); FMA4(D, z3, w3);        \
    FMA4(D, z4, w4); FMA4(D, z5, w5); FMA4(D, z6, w6); FMA4(D, z7, w7)

__device__ __forceinline__ float pairwise_zsq(f4 z0, f4 z1, f4 z2, f4 z3,
                                              f4 z4, f4 z5, f4 z6, f4 z7) {
#define SQ_(a) __fmul_rn((a), (a))
#define R4_(a, b, c, d) \
    __fadd_rn(__fadd_rn(__fadd_rn(SQ_(a), SQ_(b)), SQ_(c)), SQ_(d))
    float r0 = R4_(z0.x, z2.x, z4.x, z6.x);
    float r1 = R4_(z0.y, z2.y, z4.y, z6.y);
    float r2 = R4_(z0.z, z2.z, z4.z, z6.z);
    float r3 = R4_(z0.w, z2.w, z4.w, z6.w);
    float r4 = R4_(z1.x, z3.x, z5.x, z7.x);
    float r5 = R4_(z1.y, z3.y, z5.y, z7.y);
    float r6 = R4_(z1.z, z3.z, z5.z, z7.z);
    float r7 = R4_(z1.w, z3.w, z5.w, z7.w);
    return __fadd_rn(__fadd_rn(__fadd_rn(r0, r1), __fadd_rn(r2, r3)),
                     __fadd_rn(__fadd_rn(r4, r5), __fadd_rn(r6, r7)));
#undef R4_
#undef SQ_
}

struct Shm {
    float cd[256];
    int   ci[256];
    float zql[256];
    float rest[256];
};

// ---------------- init: plane means of z_enc -> zflat (L0 tokens); ||e||^2 --
__device__ void init_phase(int bid, const float* __restrict__ z_enc,
                           const float* __restrict__ emb,
                           float* zflat, float* wsq, Shm& sh) {
    int t = threadIdx.x;
    for (int p = bid; p < 2048; p += 1024) {
        float v = z_enc[p * 256 + t];
        for (int o = 32; o > 0; o >>= 1) v += __shfl_down(v, o, 64);
        if ((t & 63) == 0) sh.rest[t >> 6] = v;
        __syncthreads();
        if (t == 0)
            zflat[p] = (sh.rest[0] + sh.rest[1] + sh.rest[2] + sh.rest[3]) * (1.f / 256.f);
        __syncthreads();
    }
    if (t < 128) {  // 4 codes per block: 1024 blocks x 4 = 4096
        int k = bid * 4 + (t >> 5), c = t & 31;
        float e = emb[k * 32 + c];
        float s = __fmul_rn(e, e);
        for (int o = 16; o > 0; o >>= 1) s += __shfl_down(s, o, 32);
        if (c == 0) wsq[k] = s;
    }
}

// ---------------- token-parallel argmin partial (levels 2..4) ---------------
template <int CPK>
__device__ void part_phase(int chunk, int slice, int T,
                           const float* __restrict__ zflat,
                           const float* __restrict__ emb,
                           const float* __restrict__ wsq,
                           float* cand_d, int* cand_i) {
    int tok = chunk * 256 + threadIdx.x;
    int k0 = slice * CPK;
    const f4* zr = (const f4*)(zflat + (size_t)tok * 32);
    f4 z0 = zr[0], z1 = zr[1], z2 = zr[2], z3 = zr[3];
    f4 z4 = zr[4], z5 = zr[5], z6 = zr[6], z7 = zr[7];
    // pin z into VGPRs: forbid the compiler from re-loading per iteration
    asm volatile("" : "+v"(z0), "+v"(z1), "+v"(z2), "+v"(z3),
                      "+v"(z4), "+v"(z5), "+v"(z6), "+v"(z7));
    float zsq = pairwise_zsq(z0, z1, z2, z3, z4, z5, z6, z7);

    float best = 1e30f;
    int bi = 0;
#pragma unroll 2
    for (int k = k0; k < k0 + CPK; k++) {
        const f4* wr = (const f4*)emb + (size_t)k * 8;  // wave-uniform -> s_load
        f4 w0 = wr[0], w1 = wr[1], w2 = wr[2], w3 = wr[3];
        f4 w4 = wr[4], w5 = wr[5], w6 = wr[6], w7 = wr[7];
        float dot = 0.f;
        DOT32(dot);
        float d = __fsub_rn(__fadd_rn(zsq, wsq[k]), __fadd_rn(dot, dot));
        if (d < best) { best = d; bi = k; }  // strict < keeps lowest k
    }
    cand_d[(size_t)slice * T + tok] = best;
    cand_i[(size_t)slice * T + tok] = bi;
}

// ---------------- k-parallel argmin partial (levels 0,1) --------------------
template <int KPL>
__device__ void partk_phase(int tok, int slice, int T,
                            const float* __restrict__ zflat,
                            const float* __restrict__ emb,
                            const float* __restrict__ wsq,
                            float* cand_d, int* cand_i) {
    int lane = threadIdx.x & 63;
    const f4* zr = (const f4*)(zflat + (size_t)tok * 32);
    f4 z0 = zr[0], z1 = zr[1], z2 = zr[2], z3 = zr[3];
    f4 z4 = zr[4], z5 = zr[5], z6 = zr[6], z7 = zr[7];
    float zsq = pairwise_zsq(z0, z1, z2, z3, z4, z5, z6, z7);

    float best = 1e30f;
    int bi = 0x7fffffff;
#pragma unroll
    for (int j = 0; j < KPL; j++) {
        int k = slice * (KPL * 64) + j * 64 + lane;
        const f4* wr = (const f4*)emb + (size_t)k * 8;
        f4 w0 = wr[0], w1 = wr[1], w2 = wr[2], w3 = wr[3];
        f4 w4 = wr[4], w5 = wr[5], w6 = wr[6], w7 = wr[7];
        float dot = 0.f;
        DOT32(dot);
        float d = __fsub_rn(__fadd_rn(zsq, wsq[k]), __fadd_rn(dot, dot));
        if (d < best) { best = d; bi = k; }
    }
    for (int off = 32; off > 0; off >>= 1) {  // lex (d, k) min, first-index tie
        float od = __shfl_down(best, off, 64);
        int oi = __shfl_down(bi, off, 64);
        if (od < best || (od == best && oi < bi)) { best = od; bi = oi; }
    }
    if (lane == 0) {
        cand_d[(size_t)slice * T + tok] = best;
        cand_i[(size_t)slice * T + tok] = bi;
    }
}

// ---------------- fused combine + upsample + out + z_rest + next zflat ------
template <int PN, int PNn, int KS>
__device__ void apply_phase(int plane, int lvl, const float* __restrict__ z_enc,
                            const float* __restrict__ emb, float* out,
                            float* zrest, float* zflat,
                            const float* cand_d, const int* cand_i, Shm& sh) {
    constexpr int TP = PN * PN;
    constexpr int Tl = 64 * TP;
    constexpr int G = 256 / TP;
    constexpr int Geff = (G < KS) ? G : KS;
    int t = threadIdx.x;
    int b = plane >> 5, c = plane & 31;
    int g = t / TP, tl = t % TP;

    if (g < Geff) {  // stage 1: each group reduces its slice subset
        float best = 1e30f;
        int bi = 0x7fffffff;
        int tok = b * TP + tl;
        for (int s = g; s < KS; s += Geff) {
            float d = cand_d[(size_t)s * Tl + tok];
            int i = cand_i[(size_t)s * Tl + tok];
            if (d < best || (d == best && i < bi)) { best = d; bi = i; }
        }
        sh.cd[t] = best;
        sh.ci[t] = bi;
    }
    __syncthreads();
    if (t < TP) {  // stage 2: reduce across groups, gather code row (chan c)
        float best = sh.cd[t];
        int bi = sh.ci[t];
        for (int gg = 1; gg < Geff; gg++) {
            float d = sh.cd[gg * TP + t];
            int i = sh.ci[gg * TP + t];
            if (d < best || (d == best && i < bi)) { best = d; bi = i; }
        }
        sh.zql[t] = emb[(size_t)bi * 32 + c];
    }
    __syncthreads();

    int h = t >> 4, w = t & 15;
    float zup;
    if constexpr (PN == 16) {
        zup = sh.zql[t];
    } else {
        float wy[4], wx[4];
        int iy0, ny, jx0, nx;
        taps<PN>(h, wy, iy0, ny);
        taps<PN>(w, wx, jx0, nx);
        zup = 0.f;
        for (int e = 0; e < nx; e++) {
            float colacc = 0.f;
            for (int a = 0; a < ny; a++)
                colacc += wy[a] * sh.zql[(iy0 + a) * PN + (jx0 + e)];
            zup += wx[e] * colacc;
        }
    }
    int idx = plane * 256 + t;
    float prev = (lvl == 0) ? 0.f : out[(size_t)(lvl - 1) * OUTSZ + idx];
    out[(size_t)lvl * OUTSZ + idx] = __fadd_rn(prev, zup);

    if (lvl < 4) {
        float rv = __fsub_rn((lvl == 0 ? z_enc[idx] : zrest[idx]), zup);
        sh.rest[t] = rv;
        zrest[idx] = rv;
        __syncthreads();
        constexpr int TPn = PNn * PNn;
        constexpr int S = 16 / PNn;
        if (t < TPn) {
            int i = t / PNn, j = t % PNn;
            float s = 0.f;
            for (int di = 0; di < S; di++)
                for (int dj = 0; dj < S; dj++)
                    s = __fadd_rn(s, sh.rest[(i * S + di) * 16 + (j * S + dj)]);
            zflat[(size_t)(b * TPn + t) * 32 + c] = s * (1.f / (float)(S * S));
        }
        __syncthreads();
    } else {
        __syncthreads();
    }
}

// ---------------- the mega kernel: all 5 levels, one launch -----------------
__global__ void __launch_bounds__(256, 4) mega_kernel(
    const float* __restrict__ z_enc, const float* __restrict__ emb,
    float* __restrict__ out, float* wsq, float* zflat, float* zrest,
    float* cand_d, int* cand_i, unsigned* bar) {
    __shared__ Shm sh;
    int bid = blockIdx.x;
    int wid = threadIdx.x >> 6;
    const unsigned NBK = 1024;

    init_phase(bid, z_enc, emb, zflat, wsq, sh);
    gsync(bar, 0, NBK);

    // level 0: T=64; 64 tok x 64 slices (64 codes each) = 4096 wave-tasks
    { int wt = bid * 4 + wid; partk_phase<1>(wt >> 6, wt & 63, 64, zflat, emb, wsq, cand_d, cand_i); }
    gsync(bar, 1, NBK);
    for (int p = bid; p < 2048; p += 1024)
        apply_phase<1, 2, 64>(p, 0, z_enc, emb, out, zrest, zflat, cand_d, cand_i, sh);
    gsync(bar, 2, NBK);

    // level 1: T=256; 256 tok x 16 slices (256 codes, KPL=4) = 4096 wave-tasks
    { int wt = bid * 4 + wid; partk_phase<4>(wt >> 4, wt & 15, 256, zflat, emb, wsq, cand_d, cand_i); }
    gsync(bar, 3, NBK);
    for (int p = bid; p < 2048; p += 1024)
        apply_phase<2, 4, 16>(p, 1, z_enc, emb, out, zrest, zflat, cand_d, cand_i, sh);
    gsync(bar, 4, NBK);

    // level 2: T=1024; 4 chunks x 256 slices, CPK=16
    part_phase<16>(bid >> 8, bid & 255, 1024, zflat, emb, wsq, cand_d, cand_i);
    gsync(bar, 5, NBK);
    for (int p = bid; p < 2048; p += 1024)
        apply_phase<4, 8, 256>(p, 2, z_enc, emb, out, zrest, zflat, cand_d, cand_i, sh);
    gsync(bar, 6, NBK);

    // level 3: T=4096; 16 chunks x 64 slices, CPK=64
    part_phase<64>(bid >> 6, bid & 63, 4096, zflat, emb, wsq, cand_d, cand_i);
    gsync(bar, 7, NBK);
    for (int p = bid; p < 2048; p += 1024)
        apply_phase<8, 16, 64>(p, 3, z_enc, emb, out, zrest, zflat, cand_d, cand_i, sh);
    gsync(bar, 8, NBK);

    // level 4: T=16384; 64 chunks x 16 slices, CPK=256
    part_phase<256>(bid >> 4, bid & 15, 16384, zflat, emb, wsq, cand_d, cand_i);
    gsync(bar, 9, NBK);
    for (int p = bid; p < 2048; p += 1024)
        apply_phase<16, 16, 16>(p, 4, z_enc, emb, out, zrest, zflat, cand_d, cand_i, sh);
}

extern "C" void kernel_launch(void* const* d_in, const int* in_sizes, int n_in,
                              void* d_out, int out_size, void* d_ws, size_t ws_size,
                              hipStream_t stream) {
    const float* z_enc = (const float*)d_in[0];   // [64,32,16,16]
    const float* emb   = (const float*)d_in[1];   // [4096,32]
    float* out = (float*)d_out;                   // [5,64,32,16,16]

    unsigned* bar = (unsigned*)d_ws;              // 64 u32 barrier counters
    float* wsq    = (float*)d_ws + 64;            // 4096
    float* zflat  = wsq + 4096;                   // 524288 (token-major, C-last)
    float* zrest  = zflat + 524288;               // 524288 (plane layout)
    float* cand_d = zrest + 524288;               // 524288
    int*   cand_i = (int*)(cand_d + 524288);      // 524288

    hipMemsetAsync((void*)bar, 0, 64 * sizeof(unsigned), stream);
    mega_kernel<<<1024, 256, 0, stream>>>(z_enc, emb, out, wsq, zflat, zrest,
                                          cand_d, cand_i, bar);
}

// Round 5
// 800.718 us; speedup vs baseline: 2.4774x; 2.4774x over previous
//
#include <hip/hip_runtime.h>

#define OUTSZ 524288  // elems per output level (64*32*16*16)
typedef float f4 __attribute__((ext_vector_type(4)));

// ---------------- cubic (Keys a=-0.5), matches jax.image.resize 'cubic' ----
__device__ __forceinline__ float cubic_w(float x) {
    x = fabsf(x);
    if (x >= 2.f) return 0.f;
    if (x >= 1.f) return ((-0.5f * x + 2.5f) * x - 4.f) * x + 2.f;
    return ((1.5f * x - 2.5f) * x) * x + 1.f;
}

template <int PN>
__device__ __forceinline__ void taps(int o, float* w, int& i0, int& n) {
    float sf = (o + 0.5f) * ((float)PN / 16.f) - 0.5f;
    int lo = (int)floorf(sf) - 1;
    int hi = lo + 3;
    if (lo < 0) lo = 0;
    if (hi > PN - 1) hi = PN - 1;
    n = hi - lo + 1;
    i0 = lo;
    float tot = 0.f;
    for (int i = 0; i < n; i++) {
        float ww = cubic_w(sf - (float)(lo + i));
        w[i] = ww;
        tot += ww;
    }
    float inv = 1.f / tot;
    for (int i = 0; i < n; i++) w[i] *= inv;
}

// ---- exact-order helpers (match numpy reference rounding; do not touch) ----
#define FMA4(D, A, B)                                                          \
    D = __builtin_fmaf((A).x, (B).x, D); D = __builtin_fmaf((A).y, (B).y, D);  \
    D = __builtin_fmaf((A).z, (B).z, D); D = __builtin_fmaf((A).w, (B).w, D)
#define DOT32(D)                                                               \
    FMA4(D, z0, w0); FMA4(D, z1, w1); FMA4(D, z2, w2); FMA4(D, z3, w3);        \
    FMA4(D, z4, w4); FMA4(D, z5, w5); FMA4(D, z6, w6); FMA4(D, z7, w7)

__device__ __forceinline__ float pairwise_zsq(f4 z0, f4 z1, f4 z2, f4 z3,
                                              f4 z4, f4 z5, f4 z6, f4 z7) {
#define SQ_(a) __fmul_rn((a), (a))
#define R4_(a, b, c, d) \
    __fadd_rn(__fadd_rn(__fadd_rn(SQ_(a), SQ_(b)), SQ_(c)), SQ_(d))
    float r0 = R4_(z0.x, z2.x, z4.x, z6.x);
    float r1 = R4_(z0.y, z2.y, z4.y, z6.y);
    float r2 = R4_(z0.z, z2.z, z4.z, z6.z);
    float r3 = R4_(z0.w, z2.w, z4.w, z6.w);
    float r4 = R4_(z1.x, z3.x, z5.x, z7.x);
    float r5 = R4_(z1.y, z3.y, z5.y, z7.y);
    float r6 = R4_(z1.z, z3.z, z5.z, z7.z);
    float r7 = R4_(z1.w, z3.w, z5.w, z7.w);
    return __fadd_rn(__fadd_rn(__fadd_rn(r0, r1), __fadd_rn(r2, r3)),
                     __fadd_rn(__fadd_rn(r4, r5), __fadd_rn(r6, r7)));
#undef R4_
#undef SQ_
}

// ||e_k||^2 with the EXACT association of the 32-lane shfl_down tree used in
// the passing rounds (offsets 16,8,4,2,1).
__device__ __forceinline__ float wsq_tree(const float* __restrict__ emb, int k) {
    const f4* er = (const f4*)(emb + (size_t)k * 32);
    float a[32];
#pragma unroll
    for (int q = 0; q < 8; q++) {
        f4 v = er[q];
        a[4 * q]     = __fmul_rn(v.x, v.x);
        a[4 * q + 1] = __fmul_rn(v.y, v.y);
        a[4 * q + 2] = __fmul_rn(v.z, v.z);
        a[4 * q + 3] = __fmul_rn(v.w, v.w);
    }
#pragma unroll
    for (int off = 16; off > 0; off >>= 1)
#pragma unroll
        for (int c = 0; c < 16; c++)
            if (c < off) a[c] = __fadd_rn(a[c], a[c + off]);
    return a[0];
}

__device__ __forceinline__ void lexmin(float& bd, int& bi, float d, int i) {
    if (d < bd || (d == bd && i < bi)) { bd = d; bi = i; }
}

__device__ __forceinline__ void wave_lexred(float& bd, int& bi) {
    for (int off = 32; off > 0; off >>= 1) {
        float od = __shfl_down(bd, off, 64);
        int oi = __shfl_down(bi, off, 64);
        lexmin(bd, bi, od, oi);
    }
}

#define LOADZ_LDS(P)                                                           \
    f4 z0, z1, z2, z3, z4, z5, z6, z7;                                         \
    { const float* zp_ = (P);                                                  \
      z0.x=zp_[0]; z0.y=zp_[1]; z0.z=zp_[2]; z0.w=zp_[3];                      \
      z1.x=zp_[4]; z1.y=zp_[5]; z1.z=zp_[6]; z1.w=zp_[7];                      \
      z2.x=zp_[8]; z2.y=zp_[9]; z2.z=zp_[10]; z2.w=zp_[11];                    \
      z3.x=zp_[12]; z3.y=zp_[13]; z3.z=zp_[14]; z3.w=zp_[15];                  \
      z4.x=zp_[16]; z4.y=zp_[17]; z4.z=zp_[18]; z4.w=zp_[19];                  \
      z5.x=zp_[20]; z5.y=zp_[21]; z5.z=zp_[22]; z5.w=zp_[23];                  \
      z6.x=zp_[24]; z6.y=zp_[25]; z6.z=zp_[26]; z6.w=zp_[27];                  \
      z7.x=zp_[28]; z7.y=zp_[29]; z7.z=zp_[30]; z7.w=zp_[31]; }                \
    asm volatile("" : "+v"(z0), "+v"(z1), "+v"(z2), "+v"(z3),                  \
                      "+v"(z4), "+v"(z5), "+v"(z6), "+v"(z7));

struct ShmA {
    float wsq[4096];      // 16 KB
    float zrest[8192];    // 32 KB, plane-major [c*256 + px]
    float zuniv[64 * 33]; // 8.4 KB: zflat <-> zql <-> (pd2|pi2), stride 33
    float pd[16];
    int   pi[16];
    int   ti[64];
};

// ---------------- apply for levels 0..3 (within kernelA) --------------------
template <int PN, int PNn, int LVL>
__device__ void applyA(int b, float* __restrict__ out,
                       float* __restrict__ zflat4, ShmA& sh, float* zdec) {
    int t = threadIdx.x;
#pragma unroll
    for (int i = 0; i < 8; i++) {
        int pxg = i * 1024 + t;
        int c = pxg >> 8, p2 = pxg & 255, h = p2 >> 4, w = p2 & 15;
        float wy[4], wx[4];
        int iy0, ny, jx0, nx;
        taps<PN>(h, wy, iy0, ny);
        taps<PN>(w, wx, jx0, nx);
        float zup = 0.f;
        for (int e = 0; e < nx; e++) {
            float ca = 0.f;
            for (int a = 0; a < ny; a++)
                ca += wy[a] * sh.zuniv[((iy0 + a) * PN + (jx0 + e)) * 33 + c];
            zup += wx[e] * ca;
        }
        zdec[i] = __fadd_rn(zdec[i], zup);
        out[(size_t)LVL * OUTSZ + (size_t)b * 8192 + pxg] = zdec[i];
        float rv = __fsub_rn(sh.zrest[pxg], zup);
        if (LVL < 3) sh.zrest[pxg] = rv;
        else zflat4[((size_t)b * 256 + p2) * 32 + c] = rv;
    }
    __syncthreads();
    if (LVL < 3) {
        constexpr int S = 16 / PNn;
        constexpr int TASKS = PNn * PNn * 32;
        for (int task = t; task < TASKS; task += 1024) {
            int tok = task >> 5, c = task & 31, ii = tok / PNn, jj = tok % PNn;
            float s = 0.f;
            for (int di = 0; di < S; di++)
                for (int dj = 0; dj < S; dj++)
                    s = __fadd_rn(s, sh.zrest[c * 256 + (ii * S + di) * 16 + (jj * S + dj)]);
            sh.zuniv[tok * 33 + c] = s * (1.f / (float)(S * S));
        }
        __syncthreads();
    }
}

// ---------------- kernelA: levels 0-3, one block per batch element ----------
__global__ void __launch_bounds__(1024) kernelA(
    const float* __restrict__ z_enc, const float* __restrict__ emb,
    float* __restrict__ out, float* __restrict__ zflat4) {
    __shared__ ShmA sh;
    int b = blockIdx.x, t = threadIdx.x, lane = t & 63, wv = t >> 6;
    const float* zb = z_enc + (size_t)b * 8192;
    float zdec[8];

    // P0: stage z_rest, wsq, L0 token (plane means)
#pragma unroll
    for (int i = 0; i < 8; i++) { sh.zrest[i * 1024 + t] = zb[i * 1024 + t]; zdec[i] = 0.f; }
#pragma unroll
    for (int j = 0; j < 4; j++) { int k = j * 1024 + t; sh.wsq[k] = wsq_tree(emb, k); }
    for (int cc = wv; cc < 32; cc += 16) {
        float p[4];
#pragma unroll
        for (int s = 0; s < 4; s++) {
            float v = zb[cc * 256 + s * 64 + lane];
            for (int o = 32; o > 0; o >>= 1) v += __shfl_down(v, o, 64);
            p[s] = v;
        }
        if (lane == 0)
            sh.zuniv[cc] = (((p[0] + p[1]) + p[2]) + p[3]) * (1.f / 256.f);
    }
    __syncthreads();

    // P1: L0 part — 1 token, all 1024 lanes over codes (KPL=4)
    {
        LOADZ_LDS(&sh.zuniv[0]);
        float zsq = pairwise_zsq(z0, z1, z2, z3, z4, z5, z6, z7);
        float bd = 1e30f; int bi = 0;
#pragma unroll 1
        for (int j = 0; j < 4; j++) {
            int k = j * 1024 + t;
            const f4* wr = (const f4*)emb + (size_t)k * 8;
            f4 w0 = wr[0], w1 = wr[1], w2 = wr[2], w3 = wr[3];
            f4 w4 = wr[4], w5 = wr[5], w6 = wr[6], w7 = wr[7];
            float dot = 0.f; DOT32(dot);
            float d = __fsub_rn(__fadd_rn(zsq, sh.wsq[k]), __fadd_rn(dot, dot));
            lexmin(bd, bi, d, k);
        }
        wave_lexred(bd, bi);
        if (lane == 0) { sh.pd[wv] = bd; sh.pi[wv] = bi; }
    }
    __syncthreads();
    if (t == 0) {
        float bd = sh.pd[0]; int bi = sh.pi[0];
        for (int s = 1; s < 16; s++) lexmin(bd, bi, sh.pd[s], sh.pi[s]);
        sh.ti[0] = bi;
    }
    __syncthreads();
    if (t < 32) sh.zuniv[t] = emb[(size_t)sh.ti[0] * 32 + t];
    __syncthreads();
    applyA<1, 2, 0>(b, out, zflat4, sh, zdec);

    // P3: L1 part — 4 tokens x 4 waves (KPL=16)
    {
        int tt = wv >> 2, ss = wv & 3;
        LOADZ_LDS(&sh.zuniv[tt * 33]);
        float zsq = pairwise_zsq(z0, z1, z2, z3, z4, z5, z6, z7);
        float bd = 1e30f; int bi = 0;
#pragma unroll 1
        for (int j = 0; j < 16; j++) {
            int k = ss * 1024 + j * 64 + lane;
            const f4* wr = (const f4*)emb + (size_t)k * 8;
            f4 w0 = wr[0], w1 = wr[1], w2 = wr[2], w3 = wr[3];
            f4 w4 = wr[4], w5 = wr[5], w6 = wr[6], w7 = wr[7];
            float dot = 0.f; DOT32(dot);
            float d = __fsub_rn(__fadd_rn(zsq, sh.wsq[k]), __fadd_rn(dot, dot));
            lexmin(bd, bi, d, k);
        }
        wave_lexred(bd, bi);
        if (lane == 0) { sh.pd[wv] = bd; sh.pi[wv] = bi; }
    }
    __syncthreads();
    if (t < 4) {
        float bd = sh.pd[t * 4]; int bi = sh.pi[t * 4];
        for (int s = 1; s < 4; s++) lexmin(bd, bi, sh.pd[t * 4 + s], sh.pi[t * 4 + s]);
        sh.ti[t] = bi;
    }
    __syncthreads();
    if (t < 128) sh.zuniv[(t >> 5) * 33 + (t & 31)] = emb[(size_t)sh.ti[t >> 5] * 32 + (t & 31)];
    __syncthreads();
    applyA<2, 4, 1>(b, out, zflat4, sh, zdec);

    // P5: L2 part — 16 tokens x 1 wave each, full codebook (KPL=64)
    {
        LOADZ_LDS(&sh.zuniv[wv * 33]);
        float zsq = pairwise_zsq(z0, z1, z2, z3, z4, z5, z6, z7);
        float bd = 1e30f; int bi = 0;
#pragma unroll 1
        for (int j = 0; j < 64; j++) {
            int k = j * 64 + lane;
            const f4* wr = (const f4*)emb + (size_t)k * 8;
            f4 w0 = wr[0], w1 = wr[1], w2 = wr[2], w3 = wr[3];
            f4 w4 = wr[4], w5 = wr[5], w6 = wr[6], w7 = wr[7];
            float dot = 0.f; DOT32(dot);
            float d = __fsub_rn(__fadd_rn(zsq, sh.wsq[k]), __fadd_rn(dot, dot));
            lexmin(bd, bi, d, k);
        }
        wave_lexred(bd, bi);
        if (lane == 0) sh.ti[wv] = bi;
    }
    __syncthreads();
    if (t < 512) sh.zuniv[(t >> 5) * 33 + (t & 31)] = emb[(size_t)sh.ti[t >> 5] * 32 + (t & 31)];
    __syncthreads();
    applyA<4, 8, 2>(b, out, zflat4, sh, zdec);

    // P7: L3 part — TOKEN-parallel: lane=token, wave wv covers k slice of 256
    {
        LOADZ_LDS(&sh.zuniv[lane * 33]);
        float zsq = pairwise_zsq(z0, z1, z2, z3, z4, z5, z6, z7);
        __syncthreads();  // zuniv consumed into regs; reuse as pd2/pi2
        float bd = 1e30f; int bi = 0;
        int k0 = wv * 256;
#pragma unroll 2
        for (int k = k0; k < k0 + 256; k++) {
            const f4* wr = (const f4*)emb + (size_t)k * 8;  // wave-uniform -> s_load
            f4 w0 = wr[0], w1 = wr[1], w2 = wr[2], w3 = wr[3];
            f4 w4 = wr[4], w5 = wr[5], w6 = wr[6], w7 = wr[7];
            float dot = 0.f; DOT32(dot);
            float d = __fsub_rn(__fadd_rn(zsq, sh.wsq[k]), __fadd_rn(dot, dot));
            lexmin(bd, bi, d, k);
        }
        float* pd2 = sh.zuniv;
        int* pi2 = (int*)(sh.zuniv + 1024);
        pd2[wv * 64 + lane] = bd;
        pi2[wv * 64 + lane] = bi;
    }
    __syncthreads();
    if (t < 64) {
        float* pd2 = sh.zuniv;
        int* pi2 = (int*)(sh.zuniv + 1024);
        float bd = pd2[t]; int bi = pi2[t];
        for (int s = 1; s < 16; s++) lexmin(bd, bi, pd2[s * 64 + t], pi2[s * 64 + t]);
        sh.ti[t] = bi;
    }
    __syncthreads();
    for (int task = t; task < 2048; task += 1024)
        sh.zuniv[(task >> 5) * 33 + (task & 31)] = emb[(size_t)sh.ti[task >> 5] * 32 + (task & 31)];
    __syncthreads();
    applyA<8, 16, 3>(b, out, zflat4, sh, zdec);
}

// ---------------- kernelB: L4 partial argmin, token-parallel ----------------
__global__ void __launch_bounds__(256, 4) kernelB(
    const float* __restrict__ zflat4, const float* __restrict__ emb,
    float* __restrict__ cand_d, int* __restrict__ cand_i) {
    __shared__ float swsq[256];
    int t = threadIdx.x;
    int chunk = blockIdx.x >> 4, slice = blockIdx.x & 15;
    int k0 = slice * 256;
    swsq[t] = wsq_tree(emb, k0 + t);
    int tok = chunk * 256 + t;
    const f4* zr = (const f4*)(zflat4 + (size_t)tok * 32);
    f4 z0 = zr[0], z1 = zr[1], z2 = zr[2], z3 = zr[3];
    f4 z4 = zr[4], z5 = zr[5], z6 = zr[6], z7 = zr[7];
    asm volatile("" : "+v"(z0), "+v"(z1), "+v"(z2), "+v"(z3),
                      "+v"(z4), "+v"(z5), "+v"(z6), "+v"(z7));
    float zsq = pairwise_zsq(z0, z1, z2, z3, z4, z5, z6, z7);
    __syncthreads();
    float bd = 1e30f; int bi = 0;
#pragma unroll 2
    for (int k = k0; k < k0 + 256; k++) {
        const f4* wr = (const f4*)emb + (size_t)k * 8;  // wave-uniform -> s_load
        f4 w0 = wr[0], w1 = wr[1], w2 = wr[2], w3 = wr[3];
        f4 w4 = wr[4], w5 = wr[5], w6 = wr[6], w7 = wr[7];
        float dot = 0.f; DOT32(dot);
        float d = __fsub_rn(__fadd_rn(zsq, swsq[k - k0]), __fadd_rn(dot, dot));
        lexmin(bd, bi, d, k);
    }
    cand_d[(size_t)slice * 16384 + tok] = bd;
    cand_i[(size_t)slice * 16384 + tok] = bi;
}

// ---------------- kernelC: L4 combine + apply (identity upsample) -----------
__global__ void __launch_bounds__(256) kernelC(
    const float* __restrict__ emb, float* __restrict__ out,
    const float* __restrict__ cand_d, const int* __restrict__ cand_i) {
    int plane = blockIdx.x;
    int b = plane >> 5, c = plane & 31;
    int t = threadIdx.x;
    int tok = b * 256 + t;
    float bd = cand_d[tok];
    int bi = cand_i[tok];
    for (int s = 1; s < 16; s++)
        lexmin(bd, bi, cand_d[(size_t)s * 16384 + tok], cand_i[(size_t)s * 16384 + tok]);
    float zup = emb[(size_t)bi * 32 + c];
    size_t idx = (size_t)plane * 256 + t;
    out[4 * (size_t)OUTSZ + idx] = __fadd_rn(out[3 * (size_t)OUTSZ + idx], zup);
}

extern "C" void kernel_launch(void* const* d_in, const int* in_sizes, int n_in,
                              void* d_out, int out_size, void* d_ws, size_t ws_size,
                              hipStream_t stream) {
    const float* z_enc = (const float*)d_in[0];   // [64,32,16,16]
    const float* emb   = (const float*)d_in[1];   // [4096,32]
    float* out = (float*)d_out;                   // [5,64,32,16,16]

    float* zflat4 = (float*)d_ws;                 // 524288 (token-major [16384][32])
    float* cand_d = zflat4 + 524288;              // 16*16384
    int*   cand_i = (int*)(cand_d + 262144);      // 16*16384

    kernelA<<<64, 1024, 0, stream>>>(z_enc, emb, out, zflat4);
    kernelB<<<1024, 256, 0, stream>>>(zflat4, emb, cand_d, cand_i);
    kernelC<<<2048, 256, 0, stream>>>(emb, out, cand_d, cand_i);
}

// Round 6
// 411.159 us; speedup vs baseline: 4.8246x; 1.9475x over previous
//
#include <hip/hip_runtime.h>

#define OUTSZ 524288  // elems per output level (64*32*16*16)
typedef float f4 __attribute__((ext_vector_type(4)));

// ---------------- cubic (Keys a=-0.5), matches jax.image.resize 'cubic' ----
__device__ __forceinline__ float cubic_w(float x) {
    x = fabsf(x);
    if (x >= 2.f) return 0.f;
    if (x >= 1.f) return ((-0.5f * x + 2.5f) * x - 4.f) * x + 2.f;
    return ((1.5f * x - 2.5f) * x) * x + 1.f;
}

template <int PN>
__device__ __forceinline__ void taps(int o, float* w, int& i0, int& n) {
    float sf = (o + 0.5f) * ((float)PN / 16.f) - 0.5f;
    int lo = (int)floorf(sf) - 1;
    int hi = lo + 3;
    if (lo < 0) lo = 0;
    if (hi > PN - 1) hi = PN - 1;
    n = hi - lo + 1;
    i0 = lo;
    float tot = 0.f;
    for (int i = 0; i < n; i++) {
        float ww = cubic_w(sf - (float)(lo + i));
        w[i] = ww;
        tot += ww;
    }
    float inv = 1.f / tot;
    for (int i = 0; i < n; i++) w[i] *= inv;
}

// ---- exact-order helpers (match numpy reference rounding; do not touch) ----
#define FMA4(D, A, B)                                                          \
    D = __builtin_fmaf((A).x, (B).x, D); D = __builtin_fmaf((A).y, (B).y, D);  \
    D = __builtin_fmaf((A).z, (B).z, D); D = __builtin_fmaf((A).w, (B).w, D)
#define DOT32(D)                                                               \
    FMA4(D, z0, w0); FMA4(D, z1, w1); FMA4(D, z2, w2); FMA4(D, z3, w3);        \
    FMA4(D, z4, w4); FMA4(D, z5, w5); FMA4(D, z6, w6); FMA4(D, z7, w7)
#define LOADW(K)                                                               \
    const f4* wr = (const f4*)emb + (size_t)(K) * 8;                           \
    f4 w0 = wr[0], w1 = wr[1], w2 = wr[2], w3 = wr[3];                         \
    f4 w4 = wr[4], w5 = wr[5], w6 = wr[6], w7 = wr[7]

__device__ __forceinline__ float pairwise_zsq(f4 z0, f4 z1, f4 z2, f4 z3,
                                              f4 z4, f4 z5, f4 z6, f4 z7) {
#define SQ_(a) __fmul_rn((a), (a))
#define R4_(a, b, c, d) \
    __fadd_rn(__fadd_rn(__fadd_rn(SQ_(a), SQ_(b)), SQ_(c)), SQ_(d))
    float r0 = R4_(z0.x, z2.x, z4.x, z6.x);
    float r1 = R4_(z0.y, z2.y, z4.y, z6.y);
    float r2 = R4_(z0.z, z2.z, z4.z, z6.z);
    float r3 = R4_(z0.w, z2.w, z4.w, z6.w);
    float r4 = R4_(z1.x, z3.x, z5.x, z7.x);
    float r5 = R4_(z1.y, z3.y, z5.y, z7.y);
    float r6 = R4_(z1.z, z3.z, z5.z, z7.z);
    float r7 = R4_(z1.w, z3.w, z5.w, z7.w);
    return __fadd_rn(__fadd_rn(__fadd_rn(r0, r1), __fadd_rn(r2, r3)),
                     __fadd_rn(__fadd_rn(r4, r5), __fadd_rn(r6, r7)));
#undef R4_
#undef SQ_
}

// ||e_k||^2, exact shfl-tree association (offsets 16..1) from passing rounds
__device__ __forceinline__ float wsq_tree(const float* __restrict__ emb, int k) {
    const f4* er = (const f4*)(emb + (size_t)k * 32);
    float a[32];
#pragma unroll
    for (int q = 0; q < 8; q++) {
        f4 v = er[q];
        a[4 * q]     = __fmul_rn(v.x, v.x);
        a[4 * q + 1] = __fmul_rn(v.y, v.y);
        a[4 * q + 2] = __fmul_rn(v.z, v.z);
        a[4 * q + 3] = __fmul_rn(v.w, v.w);
    }
#pragma unroll
    for (int off = 16; off > 0; off >>= 1)
#pragma unroll
        for (int c = 0; c < 16; c++)
            if (c < off) a[c] = __fadd_rn(a[c], a[c + off]);
    return a[0];
}

__device__ __forceinline__ void lexmin(float& bd, int& bi, float d, int i) {
    if (d < bd || (d == bd && i < bi)) { bd = d; bi = i; }
}

#define PINZ asm volatile("" : "+v"(z0), "+v"(z1), "+v"(z2), "+v"(z3),        \
                               "+v"(z4), "+v"(z5), "+v"(z6), "+v"(z7))
#define ZFROM(EXPR)                                                            \
    f4 z0, z1, z2, z3, z4, z5, z6, z7;                                         \
    { float zt_[32];                                                           \
      _Pragma("unroll") for (int c_ = 0; c_ < 32; c_++) zt_[c_] = (EXPR);      \
      z0.x=zt_[0];z0.y=zt_[1];z0.z=zt_[2];z0.w=zt_[3];                         \
      z1.x=zt_[4];z1.y=zt_[5];z1.z=zt_[6];z1.w=zt_[7];                         \
      z2.x=zt_[8];z2.y=zt_[9];z2.z=zt_[10];z2.w=zt_[11];                       \
      z3.x=zt_[12];z3.y=zt_[13];z3.z=zt_[14];z3.w=zt_[15];                     \
      z4.x=zt_[16];z4.y=zt_[17];z4.z=zt_[18];z4.w=zt_[19];                     \
      z5.x=zt_[20];z5.y=zt_[21];z5.z=zt_[22];z5.w=zt_[23];                     \
      z6.x=zt_[24];z6.y=zt_[25];z6.z=zt_[26];z6.w=zt_[27];                     \
      z7.x=zt_[28];z7.y=zt_[29];z7.z=zt_[30];z7.w=zt_[31]; }                   \
    PINZ

struct ShKA {
    float wsq[4096];     // 16 KB
    float rest[32 * 257];// 32.9 KB (stride 257: bank = (c+px)%32, no conflict)
    float zf[16 * 33];   // tokens / winning rows, stride 33
    float pd[256];
    int   pi[256];
    int   ti[16];
};

// ---------------- KA: levels 0-2 per batch (+wsq side-blocks) ---------------
__global__ void __launch_bounds__(1024) kernelA(
    const float* __restrict__ z_enc, const float* __restrict__ emb,
    float* __restrict__ out, float* __restrict__ wsq_g,
    float* __restrict__ zrest_g, float* __restrict__ zflat3) {
    __shared__ ShKA sh;
    int b = blockIdx.x, t = threadIdx.x, lane = t & 63, wv = t >> 6;
    if (b >= 64) {  // wsq blocks: 64 codes each
        if (t < 64) { int k = (b - 64) * 64 + t; wsq_g[k] = wsq_tree(emb, k); }
        return;
    }
    const float* zb = z_enc + (size_t)b * 8192;
    float zdec[8];
    int px = t & 255, h = px >> 4, w = px & 15;

    // P0: stage z_enc -> rest LDS; wsq LDS; L0 token mean (exact round-5 order)
#pragma unroll
    for (int i = 0; i < 8; i++) {
        int pxg = i * 1024 + t;
        sh.rest[(pxg >> 8) * 257 + px] = zb[pxg];
        zdec[i] = 0.f;
    }
#pragma unroll
    for (int j = 0; j < 4; j++) { int k = j * 1024 + t; sh.wsq[k] = wsq_tree(emb, k); }
    for (int cc = wv; cc < 32; cc += 16) {
        float p[4];
#pragma unroll
        for (int s = 0; s < 4; s++) {
            float v = zb[cc * 256 + s * 64 + lane];
            for (int o = 32; o > 0; o >>= 1) v += __shfl_down(v, o, 64);
            p[s] = v;
        }
        if (lane == 0)
            sh.zf[cc] = (((p[0] + p[1]) + p[2]) + p[3]) * (1.f / 256.f);
    }
    __syncthreads();

    // ---- L0 part: 1 token, 4096 codes over 1024 threads ----
    {
        ZFROM(sh.zf[c_]);
        float zsq = pairwise_zsq(z0, z1, z2, z3, z4, z5, z6, z7);
        float bd = 1e30f; int bi = 0x7fffffff;
#pragma unroll 2
        for (int j = 0; j < 4; j++) {
            int k = j * 1024 + t;
            LOADW(k);
            float dot = 0.f; DOT32(dot);
            float d = __fsub_rn(__fadd_rn(zsq, sh.wsq[k]), __fadd_rn(dot, dot));
            lexmin(bd, bi, d, k);
        }
        for (int off = 32; off > 0; off >>= 1) {
            float od = __shfl_down(bd, off, 64);
            int oi = __shfl_down(bi, off, 64);
            lexmin(bd, bi, od, oi);
        }
        if (lane == 0) { sh.pd[wv] = bd; sh.pi[wv] = bi; }
    }
    __syncthreads();
    if (t == 0) {
        float bd = sh.pd[0]; int bi = sh.pi[0];
        for (int s = 1; s < 16; s++) lexmin(bd, bi, sh.pd[s], sh.pi[s]);
        sh.ti[0] = bi;
    }
    __syncthreads();
    if (t < 32) sh.zf[t] = emb[(size_t)sh.ti[0] * 32 + t];
    __syncthreads();
    // ---- apply L0 (PN=1 -> constant), downsample S=8 -> 4 tokens ----
#pragma unroll
    for (int i = 0; i < 8; i++) {
        int c = i * 4 + (t >> 8);
        float zup = sh.zf[c];
        zdec[i] = __fadd_rn(zdec[i], zup);
        out[(size_t)b * 8192 + i * 1024 + t] = zdec[i];
        sh.rest[c * 257 + px] = __fsub_rn(sh.rest[c * 257 + px], zup);
    }
    __syncthreads();
    if (t < 128) {
        int tok = t >> 5, c = t & 31, ii = tok >> 1, jj = tok & 1;
        float s = 0.f;
        for (int di = 0; di < 8; di++)
            for (int dj = 0; dj < 8; dj++)
                s = __fadd_rn(s, sh.rest[c * 257 + (ii * 8 + di) * 16 + (jj * 8 + dj)]);
        sh.zf[tok * 33 + c] = s * (1.f / 64.f);
    }
    __syncthreads();

    // ---- L1 part: 4 tokens; lane=(kgrp=lane>>2, tok=lane&3); wave=256 codes --
    {
        ZFROM(sh.zf[(lane & 3) * 33 + c_]);
        float zsq = pairwise_zsq(z0, z1, z2, z3, z4, z5, z6, z7);
        float bd = 1e30f; int bi = 0x7fffffff;
        int kb = wv * 256 + (lane >> 2) * 16;
#pragma unroll 2
        for (int j = 0; j < 16; j++) {
            int k = kb + j;
            LOADW(k);
            float dot = 0.f; DOT32(dot);
            float d = __fsub_rn(__fadd_rn(zsq, sh.wsq[k]), __fadd_rn(dot, dot));
            lexmin(bd, bi, d, k);
        }
        for (int off = 32; off >= 4; off >>= 1) {  // same-token lanes only
            float od = __shfl_down(bd, off, 64);
            int oi = __shfl_down(bi, off, 64);
            lexmin(bd, bi, od, oi);
        }
        if (lane < 4) { sh.pd[wv * 4 + lane] = bd; sh.pi[wv * 4 + lane] = bi; }
    }
    __syncthreads();
    if (t < 4) {
        float bd = sh.pd[t]; int bi = sh.pi[t];
        for (int s = 1; s < 16; s++) lexmin(bd, bi, sh.pd[s * 4 + t], sh.pi[s * 4 + t]);
        sh.ti[t] = bi;
    }
    __syncthreads();
    if (t < 128) sh.zf[(t >> 5) * 33 + (t & 31)] = emb[(size_t)sh.ti[t >> 5] * 32 + (t & 31)];
    __syncthreads();
    // ---- apply L1 (PN=2), downsample S=4 -> 16 tokens ----
    {
        float wy[4], wx[4]; int iy0, ny, jx0, nx;
        taps<2>(h, wy, iy0, ny);
        taps<2>(w, wx, jx0, nx);
#pragma unroll
        for (int i = 0; i < 8; i++) {
            int c = i * 4 + (t >> 8);
            float zup = 0.f;
            for (int e = 0; e < nx; e++) {
                float ca = 0.f;
                for (int a = 0; a < ny; a++)
                    ca += wy[a] * sh.zf[((iy0 + a) * 2 + (jx0 + e)) * 33 + c];
                zup += wx[e] * ca;
            }
            zdec[i] = __fadd_rn(zdec[i], zup);
            out[(size_t)OUTSZ + (size_t)b * 8192 + i * 1024 + t] = zdec[i];
            sh.rest[c * 257 + px] = __fsub_rn(sh.rest[c * 257 + px], zup);
        }
    }
    __syncthreads();
    if (t < 512) {
        int tok = t >> 5, c = t & 31, ii = tok >> 2, jj = tok & 3;
        float s = 0.f;
        for (int di = 0; di < 4; di++)
            for (int dj = 0; dj < 4; dj++)
                s = __fadd_rn(s, sh.rest[c * 257 + (ii * 4 + di) * 16 + (jj * 4 + dj)]);
        sh.zf[tok * 33 + c] = s * (1.f / 16.f);
    }
    __syncthreads();

    // ---- L2 part: 16 tokens; lane=(kgrp=lane>>4, tok=lane&15) ----
    {
        ZFROM(sh.zf[(lane & 15) * 33 + c_]);
        float zsq = pairwise_zsq(z0, z1, z2, z3, z4, z5, z6, z7);
        float bd = 1e30f; int bi = 0x7fffffff;
        int kb = wv * 256 + (lane >> 4) * 64;
#pragma unroll 2
        for (int j = 0; j < 64; j++) {
            int k = kb + j;
            LOADW(k);
            float dot = 0.f; DOT32(dot);
            float d = __fsub_rn(__fadd_rn(zsq, sh.wsq[k]), __fadd_rn(dot, dot));
            lexmin(bd, bi, d, k);
        }
        for (int off = 32; off >= 16; off >>= 1) {
            float od = __shfl_down(bd, off, 64);
            int oi = __shfl_down(bi, off, 64);
            lexmin(bd, bi, od, oi);
        }
        if (lane < 16) { sh.pd[wv * 16 + lane] = bd; sh.pi[wv * 16 + lane] = bi; }
    }
    __syncthreads();
    if (t < 16) {
        float bd = sh.pd[t]; int bi = sh.pi[t];
        for (int s = 1; s < 16; s++) lexmin(bd, bi, sh.pd[s * 16 + t], sh.pi[s * 16 + t]);
        sh.ti[t] = bi;
    }
    __syncthreads();
    if (t < 512) sh.zf[(t >> 5) * 33 + (t & 31)] = emb[(size_t)sh.ti[t >> 5] * 32 + (t & 31)];
    __syncthreads();
    // ---- apply L2 (PN=4) -> out[2], zrest_g, zflat3 (S=2, 64 tokens) ----
    {
        float wy[4], wx[4]; int iy0, ny, jx0, nx;
        taps<4>(h, wy, iy0, ny);
        taps<4>(w, wx, jx0, nx);
#pragma unroll
        for (int i = 0; i < 8; i++) {
            int c = i * 4 + (t >> 8);
            float zup = 0.f;
            for (int e = 0; e < nx; e++) {
                float ca = 0.f;
                for (int a = 0; a < ny; a++)
                    ca += wy[a] * sh.zf[((iy0 + a) * 4 + (jx0 + e)) * 33 + c];
                zup += wx[e] * ca;
            }
            zdec[i] = __fadd_rn(zdec[i], zup);
            out[2 * (size_t)OUTSZ + (size_t)b * 8192 + i * 1024 + t] = zdec[i];
            float rv = __fsub_rn(sh.rest[c * 257 + px], zup);
            sh.rest[c * 257 + px] = rv;
            zrest_g[(size_t)b * 8192 + i * 1024 + t] = rv;
        }
    }
    __syncthreads();
#pragma unroll
    for (int i = 0; i < 2; i++) {
        int task = i * 1024 + t;
        int tok = task >> 5, c = task & 31, ii = tok >> 3, jj = tok & 7;
        float s = 0.f;
        for (int di = 0; di < 2; di++)
            for (int dj = 0; dj < 2; dj++)
                s = __fadd_rn(s, sh.rest[c * 257 + (ii * 2 + di) * 16 + (jj * 2 + dj)]);
        zflat3[((size_t)b * 64 + tok) * 32 + c] = s * 0.25f;
    }
}

// ---------------- KD: L3 partial argmin, token-parallel, s_load k ----------
__global__ void __launch_bounds__(256, 4) kernelD(
    const float* __restrict__ zflat3, const float* __restrict__ emb,
    const float* __restrict__ wsq_g, float* __restrict__ cd3, int* __restrict__ ci3) {
    int t = threadIdx.x;
    int tok = blockIdx.x * 256 + t;      // 16 chunks
    int slice = blockIdx.y;              // 32 slices x 128 codes
    const f4* zr = (const f4*)(zflat3 + (size_t)tok * 32);
    f4 z0 = zr[0], z1 = zr[1], z2 = zr[2], z3 = zr[3];
    f4 z4 = zr[4], z5 = zr[5], z6 = zr[6], z7 = zr[7];
    PINZ;
    float zsq = pairwise_zsq(z0, z1, z2, z3, z4, z5, z6, z7);
    float bd = 1e30f; int bi = 0x7fffffff;
    int k0 = slice * 128;
#pragma unroll 2
    for (int k = k0; k < k0 + 128; k++) {  // wave-uniform -> s_load
        LOADW(k);
        float dot = 0.f; DOT32(dot);
        float d = __fsub_rn(__fadd_rn(zsq, wsq_g[k]), __fadd_rn(dot, dot));
        lexmin(bd, bi, d, k);
    }
    cd3[(size_t)slice * 4096 + tok] = bd;
    ci3[(size_t)slice * 4096 + tok] = bi;
}

// ---------------- KE: combine(L3)+apply(L3) + part(L4) ----------------------
__global__ void __launch_bounds__(256, 4) kernelE(
    const float* __restrict__ emb, const float* __restrict__ wsq_g,
    const float* __restrict__ zrest_g, float* __restrict__ out,
    const float* __restrict__ cd3, const int* __restrict__ ci3,
    float* __restrict__ cd4, int* __restrict__ ci4) {
    __shared__ float pd[256];
    __shared__ int pi[256];
    __shared__ int ti[64];
    __shared__ float zql[64 * 33];
    int b = blockIdx.x, s = blockIdx.y, t = threadIdx.x;

    {   // combine 32 slices for batch b's 64 tokens
        int tok = t & 63, grp = t >> 6;
        float bd = 1e30f; int bi = 0x7fffffff;
        for (int q = 0; q < 8; q++) {
            int s2 = grp * 8 + q;
            size_t idx = (size_t)s2 * 4096 + b * 64 + tok;
            lexmin(bd, bi, cd3[idx], ci3[idx]);
        }
        pd[t] = bd; pi[t] = bi;
    }
    __syncthreads();
    if (t < 64) {
        float bd = pd[t]; int bi = pi[t];
        for (int g = 1; g < 4; g++) lexmin(bd, bi, pd[g * 64 + t], pi[g * 64 + t]);
        ti[t] = bi;
    }
    __syncthreads();
#pragma unroll
    for (int i = 0; i < 8; i++) {
        int task = i * 256 + t;
        zql[(task >> 5) * 33 + (task & 31)] = emb[(size_t)ti[task >> 5] * 32 + (task & 31)];
    }
    __syncthreads();

    // apply L3 per thread (t = this batch's token/pixel), z into regs
    int h = t >> 4, w = t & 15;
    float wy[4], wx[4]; int iy0, ny, jx0, nx;
    taps<8>(h, wy, iy0, ny);
    taps<8>(w, wx, jx0, nx);
    float zv[32];
#pragma unroll
    for (int c = 0; c < 32; c++) {
        float zup = 0.f;
        for (int e = 0; e < nx; e++) {
            float ca = 0.f;
            for (int a = 0; a < ny; a++)
                ca += wy[a] * zql[((iy0 + a) * 8 + (jx0 + e)) * 33 + c];
            zup += wx[e] * ca;
        }
        size_t idx = (size_t)b * 8192 + c * 256 + t;
        if (s == 0)
            out[3 * (size_t)OUTSZ + idx] = __fadd_rn(out[2 * (size_t)OUTSZ + idx], zup);
        zv[c] = __fsub_rn(zrest_g[idx], zup);
    }
    ZFROM(zv[c_]);
    float zsq = pairwise_zsq(z0, z1, z2, z3, z4, z5, z6, z7);

    // part L4: this block's 256-code slice, wave-uniform s_load
    float bd = 1e30f; int bi = 0x7fffffff;
    int k0 = s * 256;
#pragma unroll 2
    for (int k = k0; k < k0 + 256; k++) {
        LOADW(k);
        float dot = 0.f; DOT32(dot);
        float d = __fsub_rn(__fadd_rn(zsq, wsq_g[k]), __fadd_rn(dot, dot));
        lexmin(bd, bi, d, k);
    }
    cd4[(size_t)s * 16384 + b * 256 + t] = bd;
    ci4[(size_t)s * 16384 + b * 256 + t] = bi;
}

// ---------------- KF: combine(L4) + apply (identity upsample) ---------------
__global__ void __launch_bounds__(256) kernelF(
    const float* __restrict__ emb, float* __restrict__ out,
    const float* __restrict__ cd4, const int* __restrict__ ci4) {
    int plane = blockIdx.x;          // b*32 + c
    int b = plane >> 5, c = plane & 31;
    int t = threadIdx.x;
    int tok = b * 256 + t;
    float bd = 1e30f; int bi = 0x7fffffff;
    for (int s = 0; s < 16; s++)
        lexmin(bd, bi, cd4[(size_t)s * 16384 + tok], ci4[(size_t)s * 16384 + tok]);
    float zup = emb[(size_t)bi * 32 + c];
    size_t idx = (size_t)plane * 256 + t;
    out[4 * (size_t)OUTSZ + idx] = __fadd_rn(out[3 * (size_t)OUTSZ + idx], zup);
}

extern "C" void kernel_launch(void* const* d_in, const int* in_sizes, int n_in,
                              void* d_out, int out_size, void* d_ws, size_t ws_size,
                              hipStream_t stream) {
    const float* z_enc = (const float*)d_in[0];   // [64,32,16,16]
    const float* emb   = (const float*)d_in[1];   // [4096,32]
    float* out = (float*)d_out;                   // [5,64,32,16,16]

    float* wsq_g  = (float*)d_ws;                 // 4096
    float* zrest  = wsq_g + 4096;                 // 524288
    float* zflat3 = zrest + 524288;               // 131072
    float* cd3    = zflat3 + 131072;              // 131072
    int*   ci3    = (int*)(cd3 + 131072);         // 131072
    float* cd4    = (float*)(ci3 + 131072);       // 262144
    int*   ci4    = (int*)(cd4 + 262144);         // 262144

    kernelA<<<128, 1024, 0, stream>>>(z_enc, emb, out, wsq_g, zrest, zflat3);
    kernelD<<<dim3(16, 32), 256, 0, stream>>>(zflat3, emb, wsq_g, cd3, ci3);
    kernelE<<<dim3(64, 16), 256, 0, stream>>>(emb, wsq_g, zrest, out, cd3, ci3, cd4, ci4);
    kernelF<<<2048, 256, 0, stream>>>(emb, out, cd4, ci4);
}

// Round 7
// 373.180 us; speedup vs baseline: 5.3156x; 1.1018x over previous
//
#include <hip/hip_runtime.h>

#define OUTSZ 524288  // elems per output level (64*32*16*16)
typedef float f4 __attribute__((ext_vector_type(4)));

// ---------------- cubic (Keys a=-0.5), matches jax.image.resize 'cubic' ----
__device__ __forceinline__ float cubic_w(float x) {
    x = fabsf(x);
    if (x >= 2.f) return 0.f;
    if (x >= 1.f) return ((-0.5f * x + 2.5f) * x - 4.f) * x + 2.f;
    return ((1.5f * x - 2.5f) * x) * x + 1.f;
}

template <int PN>
__device__ __forceinline__ void taps(int o, float* w, int& i0, int& n) {
    float sf = (o + 0.5f) * ((float)PN / 16.f) - 0.5f;
    int lo = (int)floorf(sf) - 1;
    int hi = lo + 3;
    if (lo < 0) lo = 0;
    if (hi > PN - 1) hi = PN - 1;
    n = hi - lo + 1;
    i0 = lo;
    float tot = 0.f;
    for (int i = 0; i < n; i++) {
        float ww = cubic_w(sf - (float)(lo + i));
        w[i] = ww;
        tot += ww;
    }
    float inv = 1.f / tot;
    for (int i = 0; i < n; i++) w[i] *= inv;
}

// ---- exact-order helpers (match numpy reference rounding; do not touch) ----
#define FMA4(D, A, B)                                                          \
    D = __builtin_fmaf((A).x, (B).x, D); D = __builtin_fmaf((A).y, (B).y, D);  \
    D = __builtin_fmaf((A).z, (B).z, D); D = __builtin_fmaf((A).w, (B).w, D)
#define DOT32(D)                                                               \
    FMA4(D, z0, w0); FMA4(D, z1, w1); FMA4(D, z2, w2); FMA4(D, z3, w3);        \
    FMA4(D, z4, w4); FMA4(D, z5, w5); FMA4(D, z6, w6); FMA4(D, z7, w7)
#define LOADW(K)                                                               \
    const f4* wr = (const f4*)emb + (size_t)(K) * 8;                           \
    f4 w0 = wr[0], w1 = wr[1], w2 = wr[2], w3 = wr[3];                         \
    f4 w4 = wr[4], w5 = wr[5], w6 = wr[6], w7 = wr[7]

__device__ __forceinline__ float pairwise_zsq(f4 z0, f4 z1, f4 z2, f4 z3,
                                              f4 z4, f4 z5, f4 z6, f4 z7) {
#define SQ_(a) __fmul_rn((a), (a))
#define R4_(a, b, c, d) \
    __fadd_rn(__fadd_rn(__fadd_rn(SQ_(a), SQ_(b)), SQ_(c)), SQ_(d))
    float r0 = R4_(z0.x, z2.x, z4.x, z6.x);
    float r1 = R4_(z0.y, z2.y, z4.y, z6.y);
    float r2 = R4_(z0.z, z2.z, z4.z, z6.z);
    float r3 = R4_(z0.w, z2.w, z4.w, z6.w);
    float r4 = R4_(z1.x, z3.x, z5.x, z7.x);
    float r5 = R4_(z1.y, z3.y, z5.y, z7.y);
    float r6 = R4_(z1.z, z3.z, z5.z, z7.z);
    float r7 = R4_(z1.w, z3.w, z5.w, z7.w);
    return __fadd_rn(__fadd_rn(__fadd_rn(r0, r1), __fadd_rn(r2, r3)),
                     __fadd_rn(__fadd_rn(r4, r5), __fadd_rn(r6, r7)));
#undef R4_
#undef SQ_
}

// ||e_k||^2, exact shfl-tree association (offsets 16..1) from passing rounds
__device__ __forceinline__ float wsq_tree(const float* __restrict__ emb, int k) {
    const f4* er = (const f4*)(emb + (size_t)k * 32);
    float a[32];
#pragma unroll
    for (int q = 0; q < 8; q++) {
        f4 v = er[q];
        a[4 * q]     = __fmul_rn(v.x, v.x);
        a[4 * q + 1] = __fmul_rn(v.y, v.y);
        a[4 * q + 2] = __fmul_rn(v.z, v.z);
        a[4 * q + 3] = __fmul_rn(v.w, v.w);
    }
#pragma unroll
    for (int off = 16; off > 0; off >>= 1)
#pragma unroll
        for (int c = 0; c < 16; c++)
            if (c < off) a[c] = __fadd_rn(a[c], a[c + off]);
    return a[0];
}

__device__ __forceinline__ void lexmin(float& bd, int& bi, float d, int i) {
    if (d < bd || (d == bd && i < bi)) { bd = d; bi = i; }
}

#define PINZ asm volatile("" : "+v"(z0), "+v"(z1), "+v"(z2), "+v"(z3),        \
                               "+v"(z4), "+v"(z5), "+v"(z6), "+v"(z7))
#define ZFROM(EXPR)                                                            \
    f4 z0, z1, z2, z3, z4, z5, z6, z7;                                         \
    { float zt_[32];                                                           \
      _Pragma("unroll") for (int c_ = 0; c_ < 32; c_++) zt_[c_] = (EXPR);      \
      z0.x=zt_[0];z0.y=zt_[1];z0.z=zt_[2];z0.w=zt_[3];                         \
      z1.x=zt_[4];z1.y=zt_[5];z1.z=zt_[6];z1.w=zt_[7];                         \
      z2.x=zt_[8];z2.y=zt_[9];z2.z=zt_[10];z2.w=zt_[11];                       \
      z3.x=zt_[12];z3.y=zt_[13];z3.z=zt_[14];z3.w=zt_[15];                     \
      z4.x=zt_[16];z4.y=zt_[17];z4.z=zt_[18];z4.w=zt_[19];                     \
      z5.x=zt_[20];z5.y=zt_[21];z5.z=zt_[22];z5.w=zt_[23];                     \
      z6.x=zt_[24];z6.y=zt_[25];z6.z=zt_[26];z6.w=zt_[27];                     \
      z7.x=zt_[28];z7.y=zt_[29];z7.z=zt_[30];z7.w=zt_[31]; }                   \
    PINZ

// ---------------- K0: code norms ||e_k||^2 ---------------------------------
__global__ void __launch_bounds__(256) kernel0(
    const float* __restrict__ emb, float* __restrict__ wsq_g) {
    int k = blockIdx.x * 256 + threadIdx.x;
    wsq_g[k] = wsq_tree(emb, k);
}

struct ShKA {
    float wsq[4096];     // 16 KB
    float rest[32 * 257];// 32.9 KB (stride 257: bank = (c+px)%32, no conflict)
    float zf[16 * 33];   // tokens / winning rows, stride 33
    float pd[256];
    int   pi[256];
    int   ti[16];
};

// ---------------- KA: levels 0-2, one block per batch element ---------------
__global__ void __launch_bounds__(1024) kernelA(
    const float* __restrict__ z_enc, const float* __restrict__ emb,
    float* __restrict__ out, const float* __restrict__ wsq_g,
    float* __restrict__ zrest_g, float* __restrict__ zflat3) {
    __shared__ ShKA sh;
    int b = blockIdx.x, t = threadIdx.x, lane = t & 63, wv = t >> 6;
    const float* zb = z_enc + (size_t)b * 8192;
    float zdec[8];
    int px = t & 255, h = px >> 4, w = px & 15;

    // P0: stage z_enc -> rest LDS; wsq_g -> LDS; L0 token mean
#pragma unroll
    for (int i = 0; i < 8; i++) {
        int pxg = i * 1024 + t;
        sh.rest[(pxg >> 8) * 257 + px] = zb[pxg];
        zdec[i] = 0.f;
    }
#pragma unroll
    for (int j = 0; j < 4; j++) { int k = j * 1024 + t; sh.wsq[k] = wsq_g[k]; }
    for (int cc = wv; cc < 32; cc += 16) {
        float p[4];
#pragma unroll
        for (int s = 0; s < 4; s++) {
            float v = zb[cc * 256 + s * 64 + lane];
            for (int o = 32; o > 0; o >>= 1) v += __shfl_down(v, o, 64);
            p[s] = v;
        }
        if (lane == 0)
            sh.zf[cc] = (((p[0] + p[1]) + p[2]) + p[3]) * (1.f / 256.f);
    }
    __syncthreads();

    // ---- L0 part: 1 token, 4096 codes over 1024 threads ----
    {
        ZFROM(sh.zf[c_]);
        float zsq = pairwise_zsq(z0, z1, z2, z3, z4, z5, z6, z7);
        float bd = 1e30f; int bi = 0x7fffffff;
#pragma unroll 2
        for (int j = 0; j < 4; j++) {
            int k = j * 1024 + t;
            LOADW(k);
            float dot = 0.f; DOT32(dot);
            float d = __fsub_rn(__fadd_rn(zsq, sh.wsq[k]), __fadd_rn(dot, dot));
            lexmin(bd, bi, d, k);
        }
        for (int off = 32; off > 0; off >>= 1) {
            float od = __shfl_down(bd, off, 64);
            int oi = __shfl_down(bi, off, 64);
            lexmin(bd, bi, od, oi);
        }
        if (lane == 0) { sh.pd[wv] = bd; sh.pi[wv] = bi; }
    }
    __syncthreads();
    if (t == 0) {
        float bd = sh.pd[0]; int bi = sh.pi[0];
        for (int s = 1; s < 16; s++) lexmin(bd, bi, sh.pd[s], sh.pi[s]);
        sh.ti[0] = bi;
    }
    __syncthreads();
    if (t < 32) sh.zf[t] = emb[(size_t)sh.ti[0] * 32 + t];
    __syncthreads();
    // ---- apply L0 (PN=1 -> constant), downsample S=8 -> 4 tokens ----
#pragma unroll
    for (int i = 0; i < 8; i++) {
        int c = i * 4 + (t >> 8);
        float zup = sh.zf[c];
        zdec[i] = __fadd_rn(zdec[i], zup);
        out[(size_t)b * 8192 + i * 1024 + t] = zdec[i];
        sh.rest[c * 257 + px] = __fsub_rn(sh.rest[c * 257 + px], zup);
    }
    __syncthreads();
    if (t < 128) {
        int tok = t >> 5, c = t & 31, ii = tok >> 1, jj = tok & 1;
        float s = 0.f;
        for (int di = 0; di < 8; di++)
            for (int dj = 0; dj < 8; dj++)
                s = __fadd_rn(s, sh.rest[c * 257 + (ii * 8 + di) * 16 + (jj * 8 + dj)]);
        sh.zf[tok * 33 + c] = s * (1.f / 64.f);
    }
    __syncthreads();

    // ---- L1 part: 4 tokens; lane=(kgrp=lane>>2, tok=lane&3); wave=256 codes --
    {
        ZFROM(sh.zf[(lane & 3) * 33 + c_]);
        float zsq = pairwise_zsq(z0, z1, z2, z3, z4, z5, z6, z7);
        float bd = 1e30f; int bi = 0x7fffffff;
        int kb = wv * 256 + (lane >> 2) * 16;
#pragma unroll 2
        for (int j = 0; j < 16; j++) {
            int k = kb + j;
            LOADW(k);
            float dot = 0.f; DOT32(dot);
            float d = __fsub_rn(__fadd_rn(zsq, sh.wsq[k]), __fadd_rn(dot, dot));
            lexmin(bd, bi, d, k);
        }
        for (int off = 32; off >= 4; off >>= 1) {  // same-token lanes only
            float od = __shfl_down(bd, off, 64);
            int oi = __shfl_down(bi, off, 64);
            lexmin(bd, bi, od, oi);
        }
        if (lane < 4) { sh.pd[wv * 4 + lane] = bd; sh.pi[wv * 4 + lane] = bi; }
    }
    __syncthreads();
    if (t < 4) {
        float bd = sh.pd[t]; int bi = sh.pi[t];
        for (int s = 1; s < 16; s++) lexmin(bd, bi, sh.pd[s * 4 + t], sh.pi[s * 4 + t]);
        sh.ti[t] = bi;
    }
    __syncthreads();
    if (t < 128) sh.zf[(t >> 5) * 33 + (t & 31)] = emb[(size_t)sh.ti[t >> 5] * 32 + (t & 31)];
    __syncthreads();
    // ---- apply L1 (PN=2), downsample S=4 -> 16 tokens ----
    {
        float wy[4], wx[4]; int iy0, ny, jx0, nx;
        taps<2>(h, wy, iy0, ny);
        taps<2>(w, wx, jx0, nx);
#pragma unroll
        for (int i = 0; i < 8; i++) {
            int c = i * 4 + (t >> 8);
            float zup = 0.f;
            for (int e = 0; e < nx; e++) {
                float ca = 0.f;
                for (int a = 0; a < ny; a++)
                    ca += wy[a] * sh.zf[((iy0 + a) * 2 + (jx0 + e)) * 33 + c];
                zup += wx[e] * ca;
            }
            zdec[i] = __fadd_rn(zdec[i], zup);
            out[(size_t)OUTSZ + (size_t)b * 8192 + i * 1024 + t] = zdec[i];
            sh.rest[c * 257 + px] = __fsub_rn(sh.rest[c * 257 + px], zup);
        }
    }
    __syncthreads();
    if (t < 512) {
        int tok = t >> 5, c = t & 31, ii = tok >> 2, jj = tok & 3;
        float s = 0.f;
        for (int di = 0; di < 4; di++)
            for (int dj = 0; dj < 4; dj++)
                s = __fadd_rn(s, sh.rest[c * 257 + (ii * 4 + di) * 16 + (jj * 4 + dj)]);
        sh.zf[tok * 33 + c] = s * (1.f / 16.f);
    }
    __syncthreads();

    // ---- L2 part: 16 tokens; lane=(kgrp=lane>>4, tok=lane&15) ----
    {
        ZFROM(sh.zf[(lane & 15) * 33 + c_]);
        float zsq = pairwise_zsq(z0, z1, z2, z3, z4, z5, z6, z7);
        float bd = 1e30f; int bi = 0x7fffffff;
        int kb = wv * 256 + (lane >> 4) * 64;
#pragma unroll 2
        for (int j = 0; j < 64; j++) {
            int k = kb + j;
            LOADW(k);
            float dot = 0.f; DOT32(dot);
            float d = __fsub_rn(__fadd_rn(zsq, sh.wsq[k]), __fadd_rn(dot, dot));
            lexmin(bd, bi, d, k);
        }
        for (int off = 32; off >= 16; off >>= 1) {
            float od = __shfl_down(bd, off, 64);
            int oi = __shfl_down(bi, off, 64);
            lexmin(bd, bi, od, oi);
        }
        if (lane < 16) { sh.pd[wv * 16 + lane] = bd; sh.pi[wv * 16 + lane] = bi; }
    }
    __syncthreads();
    if (t < 16) {
        float bd = sh.pd[t]; int bi = sh.pi[t];
        for (int s = 1; s < 16; s++) lexmin(bd, bi, sh.pd[s * 16 + t], sh.pi[s * 16 + t]);
        sh.ti[t] = bi;
    }
    __syncthreads();
    if (t < 512) sh.zf[(t >> 5) * 33 + (t & 31)] = emb[(size_t)sh.ti[t >> 5] * 32 + (t & 31)];
    __syncthreads();
    // ---- apply L2 (PN=4) -> out[2], zrest_g, zflat3 (S=2, 64 tokens) ----
    {
        float wy[4], wx[4]; int iy0, ny, jx0, nx;
        taps<4>(h, wy, iy0, ny);
        taps<4>(w, wx, jx0, nx);
#pragma unroll
        for (int i = 0; i < 8; i++) {
            int c = i * 4 + (t >> 8);
            float zup = 0.f;
            for (int e = 0; e < nx; e++) {
                float ca = 0.f;
                for (int a = 0; a < ny; a++)
                    ca += wy[a] * sh.zf[((iy0 + a) * 4 + (jx0 + e)) * 33 + c];
                zup += wx[e] * ca;
            }
            zdec[i] = __fadd_rn(zdec[i], zup);
            out[2 * (size_t)OUTSZ + (size_t)b * 8192 + i * 1024 + t] = zdec[i];
            float rv = __fsub_rn(sh.rest[c * 257 + px], zup);
            sh.rest[c * 257 + px] = rv;
            zrest_g[(size_t)b * 8192 + i * 1024 + t] = rv;
        }
    }
    __syncthreads();
#pragma unroll
    for (int i = 0; i < 2; i++) {
        int task = i * 1024 + t;
        int tok = task >> 5, c = task & 31, ii = tok >> 3, jj = tok & 7;
        float s = 0.f;
        for (int di = 0; di < 2; di++)
            for (int dj = 0; dj < 2; dj++)
                s = __fadd_rn(s, sh.rest[c * 257 + (ii * 2 + di) * 16 + (jj * 2 + dj)]);
        zflat3[((size_t)b * 64 + tok) * 32 + c] = s * 0.25f;
    }
}

// ---------------- KD: L3 partial argmin, token-parallel, s_load k ----------
__global__ void __launch_bounds__(256, 4) kernelD(
    const float* __restrict__ zflat3, const float* __restrict__ emb,
    const float* __restrict__ wsq_g, float* __restrict__ cd3, int* __restrict__ ci3) {
    int t = threadIdx.x;
    int tok = blockIdx.x * 256 + t;      // 16 chunks
    int slice = blockIdx.y;              // 32 slices x 128 codes
    const f4* zr = (const f4*)(zflat3 + (size_t)tok * 32);
    f4 z0 = zr[0], z1 = zr[1], z2 = zr[2], z3 = zr[3];
    f4 z4 = zr[4], z5 = zr[5], z6 = zr[6], z7 = zr[7];
    PINZ;
    float zsq = pairwise_zsq(z0, z1, z2, z3, z4, z5, z6, z7);
    float bd = 1e30f; int bi = 0x7fffffff;
    int k0 = slice * 128;
#pragma unroll 2
    for (int k = k0; k < k0 + 128; k++) {  // wave-uniform -> s_load
        LOADW(k);
        float dot = 0.f; DOT32(dot);
        float d = __fsub_rn(__fadd_rn(zsq, wsq_g[k]), __fadd_rn(dot, dot));
        lexmin(bd, bi, d, k);
    }
    cd3[(size_t)slice * 4096 + tok] = bd;
    ci3[(size_t)slice * 4096 + tok] = bi;
}

// ---------------- KE1: combine(L3) + apply(L3) + write zflat4 ---------------
__global__ void __launch_bounds__(256) kernelE1(
    const float* __restrict__ emb, const float* __restrict__ zrest_g,
    float* __restrict__ out, const float* __restrict__ cd3,
    const int* __restrict__ ci3, float* __restrict__ zflat4) {
    __shared__ float pd[256];
    __shared__ int pi[256];
    __shared__ int ti[64];
    __shared__ float zql[64 * 33];
    int b = blockIdx.x, t = threadIdx.x;

    {   // combine 32 slices for batch b's 64 tokens
        int tok = t & 63, grp = t >> 6;
        float bd = 1e30f; int bi = 0x7fffffff;
        for (int q = 0; q < 8; q++) {
            int s2 = grp * 8 + q;
            size_t idx = (size_t)s2 * 4096 + b * 64 + tok;
            lexmin(bd, bi, cd3[idx], ci3[idx]);
        }
        pd[t] = bd; pi[t] = bi;
    }
    __syncthreads();
    if (t < 64) {
        float bd = pd[t]; int bi = pi[t];
        for (int g = 1; g < 4; g++) lexmin(bd, bi, pd[g * 64 + t], pi[g * 64 + t]);
        ti[t] = bi;
    }
    __syncthreads();
#pragma unroll
    for (int i = 0; i < 8; i++) {
        int task = i * 256 + t;
        zql[(task >> 5) * 33 + (task & 31)] = emb[(size_t)ti[task >> 5] * 32 + (task & 31)];
    }
    __syncthreads();

    // apply L3 per thread (t = this batch's pixel/token), write zflat4 row
    int h = t >> 4, w = t & 15;
    float wy[4], wx[4]; int iy0, ny, jx0, nx;
    taps<8>(h, wy, iy0, ny);
    taps<8>(w, wx, jx0, nx);
    float zv[32];
#pragma unroll
    for (int c = 0; c < 32; c++) {
        float zup = 0.f;
        for (int e = 0; e < nx; e++) {
            float ca = 0.f;
            for (int a = 0; a < ny; a++)
                ca += wy[a] * zql[((iy0 + a) * 8 + (jx0 + e)) * 33 + c];
            zup += wx[e] * ca;
        }
        size_t idx = (size_t)b * 8192 + c * 256 + t;
        out[3 * (size_t)OUTSZ + idx] = __fadd_rn(out[2 * (size_t)OUTSZ + idx], zup);
        zv[c] = __fsub_rn(zrest_g[idx], zup);
    }
    f4* zf = (f4*)(zflat4 + ((size_t)b * 256 + t) * 32);
#pragma unroll
    for (int q = 0; q < 8; q++) {
        f4 v; v.x = zv[4 * q]; v.y = zv[4 * q + 1]; v.z = zv[4 * q + 2]; v.w = zv[4 * q + 3];
        zf[q] = v;
    }
}

// ---------------- KB2: L4 partial argmin, 2048 blocks, full occupancy -------
__global__ void __launch_bounds__(256, 8) kernelB2(
    const float* __restrict__ zflat4, const float* __restrict__ emb,
    const float* __restrict__ wsq_g, float* __restrict__ cd4, int* __restrict__ ci4) {
    int t = threadIdx.x;
    int tok = blockIdx.x * 256 + t;      // 64 chunks
    int slice = blockIdx.y;              // 32 slices x 128 codes
    const f4* zr = (const f4*)(zflat4 + (size_t)tok * 32);
    f4 z0 = zr[0], z1 = zr[1], z2 = zr[2], z3 = zr[3];
    f4 z4 = zr[4], z5 = zr[5], z6 = zr[6], z7 = zr[7];
    PINZ;
    float zsq = pairwise_zsq(z0, z1, z2, z3, z4, z5, z6, z7);
    float bd = 1e30f; int bi = 0x7fffffff;
    int k0 = slice * 128;
#pragma unroll 2
    for (int k = k0; k < k0 + 128; k++) {  // wave-uniform -> s_load
        LOADW(k);
        float dot = 0.f; DOT32(dot);
        float d = __fsub_rn(__fadd_rn(zsq, wsq_g[k]), __fadd_rn(dot, dot));
        lexmin(bd, bi, d, k);
    }
    cd4[(size_t)slice * 16384 + tok] = bd;
    ci4[(size_t)slice * 16384 + tok] = bi;
}

// ---------------- KF: combine(L4) + apply (identity upsample) ---------------
__global__ void __launch_bounds__(256) kernelF(
    const float* __restrict__ emb, float* __restrict__ out,
    const float* __restrict__ cd4, const int* __restrict__ ci4) {
    int plane = blockIdx.x;          // b*32 + c
    int b = plane >> 5, c = plane & 31;
    int t = threadIdx.x;
    int tok = b * 256 + t;
    float bd = 1e30f; int bi = 0x7fffffff;
    for (int s = 0; s < 32; s++)
        lexmin(bd, bi, cd4[(size_t)s * 16384 + tok], ci4[(size_t)s * 16384 + tok]);
    float zup = emb[(size_t)bi * 32 + c];
    size_t idx = (size_t)plane * 256 + t;
    out[4 * (size_t)OUTSZ + idx] = __fadd_rn(out[3 * (size_t)OUTSZ + idx], zup);
}

extern "C" void kernel_launch(void* const* d_in, const int* in_sizes, int n_in,
                              void* d_out, int out_size, void* d_ws, size_t ws_size,
                              hipStream_t stream) {
    const float* z_enc = (const float*)d_in[0];   // [64,32,16,16]
    const float* emb   = (const float*)d_in[1];   // [4096,32]
    float* out = (float*)d_out;                   // [5,64,32,16,16]

    float* wsq_g  = (float*)d_ws;                 // 4096
    float* zrest  = wsq_g + 4096;                 // 524288
    float* zflat3 = zrest + 524288;               // 131072
    float* cd3    = zflat3 + 131072;              // 131072
    int*   ci3    = (int*)(cd3 + 131072);         // 131072
    float* zflat4 = (float*)(ci3 + 131072);       // 524288
    float* cd4    = zflat4 + 524288;              // 524288 (32 x 16384)
    int*   ci4    = (int*)(cd4 + 524288);         // 524288

    kernel0<<<16, 256, 0, stream>>>(emb, wsq_g);
    kernelA<<<64, 1024, 0, stream>>>(z_enc, emb, out, wsq_g, zrest, zflat3);
    kernelD<<<dim3(16, 32), 256, 0, stream>>>(zflat3, emb, wsq_g, cd3, ci3);
    kernelE1<<<64, 256, 0, stream>>>(emb, zrest, out, cd3, ci3, zflat4);
    kernelB2<<<dim3(64, 32), 256, 0, stream>>>(zflat4, emb, wsq_g, cd4, ci4);
    kernelF<<<2048, 256, 0, stream>>>(emb, out, cd4, ci4);
}